// Round 2
// baseline (31.842 us; speedup 1.0000x reference)
//
#include <hip/hip_runtime.h>
#include <math.h>

#define D_MODEL 1024
#define SEQ_L   4096
#define T_CHUNK 32
#define CPR     128     // chunks per d-row (SEQ_L / T_CHUNK)

// out[d][t]: t==0 -> h0[d]; t>=1 -> sum_m Re( (Rre+i*Rim) * (r e^{i th})^(t-1) )
// Thread layout: gid -> wave = gid>>6 (lanes share d); lane>>5 = m-group
// (0: m 0..7, 1: m 8..15); chunk c = (wave&3)*32 + (lane&31); d = wave>>2.
// Each thread: 8 modes x 32 timesteps, complex-rotation recurrence, seeds via
// binary exponentiation of W^32 (no divergent transcendentals, no fp64).
// Lane-pair (lane ^ 32) butterfly reduce sums the two m-groups.
__global__ __launch_bounds__(256, 4) void pcmf_kernel(
    const float* __restrict__ r_,
    const float* __restrict__ th_,
    const float* __restrict__ Rre_,
    const float* __restrict__ Rim_,
    const float* __restrict__ h0_,
    float* __restrict__ out)
{
    const int gid  = blockIdx.x * 256 + threadIdx.x;
    const int lane = gid & 63;
    const int wave = gid >> 6;
    const int mg   = lane >> 5;                       // m-group
    const int c    = (wave & 3) * 32 + (lane & 31);   // chunk index in row
    const int d    = __builtin_amdgcn_readfirstlane(wave >> 2);
    const int t0   = c * T_CHUNK;

    float vals[T_CHUNK];
#pragma unroll
    for (int j = 0; j < T_CHUNK; ++j) vals[j] = 0.0f;

    const int mbase = mg * 8;

#pragma unroll
    for (int mp = 0; mp < 4; ++mp) {
        // ---- two modes per iteration: independent chains for ILP ----
        const int ia = (mbase + 2 * mp) * D_MODEL + d;
        const int ib = ia + D_MODEL;

        const float ra  = r_[ia],   rb  = r_[ib];
        const float tha = th_[ia],  thb = th_[ib];
        const float Rra = Rre_[ia], Rrb = Rre_[ib];
        const float Ria = Rim_[ia], Rib = Rim_[ib];

        float sna, csa, snb, csb;
        sincosf(tha, &sna, &csa);          // wave-uniform-ish arg (2 vals/wave)
        sincosf(thb, &snb, &csb);

        const float cra = ra * csa, sra = ra * sna;
        const float crb = rb * csb, srb = rb * snb;

        // A = (Rre + i Rim) * W^{-1} = (Rre + i Rim)*(cs - i sn)/r
        const float inva = 1.0f / ra, invb = 1.0f / rb;
        const float Axa = (Rra * csa + Ria * sna) * inva;
        const float Aya = (Ria * csa - Rra * sna) * inva;
        const float Axb = (Rrb * csb + Rib * snb) * invb;
        const float Ayb = (Rib * csb - Rrb * snb) * invb;

        // W32 = W^32 via 5 squarings
        float wxa = cra, wya = sra, wxb = crb, wyb = srb;
#pragma unroll
        for (int k = 0; k < 5; ++k) {
            float na = fmaf(wxa, wxa, -wya * wya); wya = 2.0f * wxa * wya; wxa = na;
            float nb = fmaf(wxb, wxb, -wyb * wyb); wyb = 2.0f * wxb * wyb; wxb = nb;
        }

        // P = (W32)^c, branchless 7-bit binary exponentiation
        float pxa = 1.0f, pya = 0.0f, pxb = 1.0f, pyb = 0.0f;
        float sxa = wxa, sya = wya, sxb = wxb, syb = wyb;
#pragma unroll
        for (int k = 0; k < 7; ++k) {
            const bool bit = (c >> k) & 1;
            float nxa = fmaf(pxa, sxa, -pya * sya);
            float nya = fmaf(pxa, sya,  pya * sxa);
            float nxb = fmaf(pxb, sxb, -pyb * syb);
            float nyb = fmaf(pxb, syb,  pyb * sxb);
            pxa = bit ? nxa : pxa;  pya = bit ? nya : pya;
            pxb = bit ? nxb : pxb;  pyb = bit ? nyb : pyb;
            if (k < 6) {
                float qa = fmaf(sxa, sxa, -sya * sya); sya = 2.0f * sxa * sya; sxa = qa;
                float qb = fmaf(sxb, sxb, -syb * syb); syb = 2.0f * sxb * syb; sxb = qb;
            }
        }

        // u = A * P  (= (Rre+i Rim) * r^{t0-1} e^{i(t0-1)th})
        float uxa = fmaf(Axa, pxa, -Aya * pya);
        float uya = fmaf(Axa, pya,  Aya * pxa);
        float uxb = fmaf(Axb, pxb, -Ayb * pyb);
        float uyb = fmaf(Axb, pyb,  Ayb * pxb);

        // ---- 32-step rotation, 5 ops per mode per step ----
#pragma unroll
        for (int j = 0; j < T_CHUNK; ++j) {
            vals[j] += uxa;
            vals[j] += uxb;
            float ta = uya * sra;
            float na = fmaf(uxa, cra, -ta);
            uya = fmaf(uxa, sra, uya * cra);
            uxa = na;
            float tb = uyb * srb;
            float nb = fmaf(uxb, crb, -tb);
            uyb = fmaf(uxb, srb, uyb * crb);
            uxb = nb;
        }
    }

    // ---- lane-pair reduce: sum m-groups ----
#pragma unroll
    for (int j = 0; j < T_CHUNK; ++j)
        vals[j] += __shfl_xor(vals[j], 32);

    if (t0 == 0) vals[0] = h0_[d];

    float* rowp = out + (size_t)d * SEQ_L + t0;
    if (mg == 0) {
#pragma unroll
        for (int k = 0; k < 4; ++k)
            *(float4*)(rowp + 4 * k) =
                make_float4(vals[4*k], vals[4*k+1], vals[4*k+2], vals[4*k+3]);
    } else {
#pragma unroll
        for (int k = 0; k < 4; ++k)
            *(float4*)(rowp + 16 + 4 * k) =
                make_float4(vals[16+4*k], vals[17+4*k], vals[18+4*k], vals[19+4*k]);
    }
}

extern "C" void kernel_launch(void* const* d_in, const int* in_sizes, int n_in,
                              void* d_out, int out_size, void* d_ws, size_t ws_size,
                              hipStream_t stream) {
    // inputs: [0]=L (scalar), [1]=r, [2]=theta, [3]=R_re, [4]=R_im, [5]=h_0
    const float* r_   = (const float*)d_in[1];
    const float* th_  = (const float*)d_in[2];
    const float* Rre_ = (const float*)d_in[3];
    const float* Rim_ = (const float*)d_in[4];
    const float* h0_  = (const float*)d_in[5];
    float* out = (float*)d_out;

    const int total_threads = D_MODEL * CPR * 2;   // 262144 (x2: m split)
    const int block = 256;
    const int grid  = total_threads / block;       // 1024
    pcmf_kernel<<<grid, block, 0, stream>>>(r_, th_, Rre_, Rim_, h0_, out);
}

// Round 3
// 24.853 us; speedup vs baseline: 1.2812x; 1.2812x over previous
//
#include <hip/hip_runtime.h>

#define D_MODEL 1024
#define SEQ_L   4096

// out[d][t]: t==0 -> h0[d]; t>=1 -> sum_m Re( (Rre+i*Rim) * (r e^{i th})^(t-1) )
//
// Layout: wave -> d = wave>>3, tblk = wave&7 (512 t each). Lane -> g = lane>>4
// (mode group: modes 4g..4g+3), k = lane&15 (chunk). Chunk c = tblk*16+k,
// t0 = 32c. Each thread: 4 modes x 32 t via complex-rotation recurrence,
// seeded by 7-bit binary exponentiation of W^32 (hw trig, no sincosf).
// Reduce 4 mode groups with shfl_xor(16/32); g==0 lanes store 32 floats.
__global__ __launch_bounds__(256, 8) void pcmf_kernel(
    const float* __restrict__ r_,
    const float* __restrict__ th_,
    const float* __restrict__ Rre_,
    const float* __restrict__ Rim_,
    const float* __restrict__ h0_,
    float* __restrict__ out)
{
    const int tid  = blockIdx.x * 256 + threadIdx.x;
    const int lane = tid & 63;
    const int wave = tid >> 6;          // 8192 waves total
    const int g    = lane >> 4;         // mode group 0..3
    const int k    = lane & 15;         // chunk-in-block
    const int tblk = wave & 7;
    const int d    = wave >> 3;         // 0..1023 (wave-uniform)
    const int c    = tblk * 16 + k;     // chunk 0..127
    const int t0   = c * 32;

    // ---- hoisted param loads: this thread's 4 modes ----
    float rr[4], tt[4], Re[4], Im[4];
    const int base = g * 4 * D_MODEL + d;
#pragma unroll
    for (int m = 0; m < 4; ++m) {
        const int idx = base + m * D_MODEL;
        rr[m] = r_[idx];
        tt[m] = th_[idx];
        Re[m] = Rre_[idx];
        Im[m] = Rim_[idx];
    }

    float Wx[4], Wy[4], ux[4], uy[4];
#pragma unroll
    for (int m = 0; m < 4; ++m) {
        // hw trig: v_sin/v_cos take revolutions; th/(2pi) in [0,1) needs no
        // range reduction and no divergent slow path.
        const float rev = tt[m] * 0.15915494309189535f;
        const float sn  = __builtin_amdgcn_sinf(rev);
        const float cs  = __builtin_amdgcn_cosf(rev);
        const float wx  = rr[m] * cs;
        const float wy  = rr[m] * sn;
        Wx[m] = wx; Wy[m] = wy;

        // A = (Re + i Im) * W^{-1} = (Re + i Im) * conj(W) / r^2
        const float invr2 = __builtin_amdgcn_rcpf(rr[m] * rr[m]);
        const float Ax = fmaf(Re[m], wx,  Im[m] * wy) * invr2;
        const float Ay = fmaf(Im[m], wx, -(Re[m] * wy)) * invr2;

        // s = W^32 via 5 complex squarings
        float sx = wx, sy = wy;
#pragma unroll
        for (int q = 0; q < 5; ++q) {
            const float nx = fmaf(sx, sx, -(sy * sy));
            sy = 2.0f * sx * sy;
            sx = nx;
        }

        // P = (W^32)^c, branchless 7-bit binexp (c < 128)
        float px = 1.0f, py = 0.0f;
#pragma unroll
        for (int b = 0; b < 7; ++b) {
            const float nx = fmaf(px, sx, -(py * sy));
            const float ny = fmaf(px, sy,   py * sx);
            const bool bit = (c >> b) & 1;
            px = bit ? nx : px;
            py = bit ? ny : py;
            if (b < 6) {
                const float qx = fmaf(sx, sx, -(sy * sy));
                sy = 2.0f * sx * sy;
                sx = qx;
            }
        }

        // u = A * P = (Re + i Im) * p^(32c - 1)
        ux[m] = fmaf(Ax, px, -(Ay * py));
        uy[m] = fmaf(Ax, py,   Ay * px);
    }

    float vals[32];
#pragma unroll
    for (int j = 0; j < 32; ++j) vals[j] = 0.0f;

    // ---- 32 steps x 4 interleaved mode chains: 20 insts issue per 8-cyc chain ----
#pragma unroll
    for (int j = 0; j < 32; ++j) {
#pragma unroll
        for (int m = 0; m < 4; ++m) {
            vals[j] += ux[m];
            const float t  = uy[m] * Wy[m];
            const float nx = fmaf(ux[m], Wx[m], -t);
            uy[m] = fmaf(ux[m], Wy[m], uy[m] * Wx[m]);
            ux[m] = nx;
        }
    }

    // ---- reduce the 4 mode groups (lanes differ only in g) ----
#pragma unroll
    for (int j = 0; j < 32; ++j) {
        vals[j] += __shfl_xor(vals[j], 16);
        vals[j] += __shfl_xor(vals[j], 32);
    }

    if (g == 0) {
        if (c == 0) vals[0] = h0_[d];
        float* p = out + (size_t)d * SEQ_L + t0;
#pragma unroll
        for (int q = 0; q < 8; ++q)
            *(float4*)(p + 4 * q) =
                make_float4(vals[4*q], vals[4*q+1], vals[4*q+2], vals[4*q+3]);
    }
}

extern "C" void kernel_launch(void* const* d_in, const int* in_sizes, int n_in,
                              void* d_out, int out_size, void* d_ws, size_t ws_size,
                              hipStream_t stream) {
    // inputs: [0]=L (scalar), [1]=r, [2]=theta, [3]=R_re, [4]=R_im, [5]=h_0
    const float* r_   = (const float*)d_in[1];
    const float* th_  = (const float*)d_in[2];
    const float* Rre_ = (const float*)d_in[3];
    const float* Rim_ = (const float*)d_in[4];
    const float* h0_  = (const float*)d_in[5];
    float* out = (float*)d_out;

    const int total_threads = D_MODEL * 8 * 64;    // 524288
    const int block = 256;
    const int grid  = total_threads / block;       // 2048 blocks, 8192 waves
    pcmf_kernel<<<grid, block, 0, stream>>>(r_, th_, Rre_, Rim_, h0_, out);
}

// Round 4
// 20.705 us; speedup vs baseline: 1.5379x; 1.2003x over previous
//
#include <hip/hip_runtime.h>

#define D_MODEL 1024
#define SEQ_L   4096

// out[d][t]: t==0 -> h0[d]; t>=1 -> sum_m Re( (Rre+i*Rim) * (r e^{i th})^(t-1) )
//
// Wave -> d = wave>>2, tblk = wave&3. Lane -> g = lane>>4 (modes 4g..4g+3),
// k = lane&15. Chunk c = tblk*16+k (64 chunks of 64 t each), t0 = 64c.
// Each thread: 4 modes x 64 t (two 32-t halves sharing ONE seed; vals[] regs
// reused after flushing half 0 to global). Seed u = (Rre+i*Rim)*W^(t0-1) via
// hw trig (revolutions) + 6 squarings (W^64) + 6-bit branchless binexp.
// 4 independent rotation chains/thread -> issue-bound per wave.
// Reduce 4 mode groups with shfl_xor(16/32); g==0 lanes store.
__global__ __launch_bounds__(256, 4) void pcmf_kernel(
    const float* __restrict__ r_,
    const float* __restrict__ th_,
    const float* __restrict__ Rre_,
    const float* __restrict__ Rim_,
    const float* __restrict__ h0_,
    float* __restrict__ out)
{
    const int tid  = blockIdx.x * 256 + threadIdx.x;
    const int lane = tid & 63;
    const int wave = tid >> 6;          // 4096 waves total (4/SIMD)
    const int g    = lane >> 4;         // mode group 0..3
    const int k    = lane & 15;
    const int tblk = wave & 3;
    const int d    = wave >> 2;         // 0..1023 (wave-uniform)
    const int c    = tblk * 16 + k;     // chunk 0..63
    const int t0   = c * 64;

    // ---- seed 4 modes at q0 = t0-1 ----
    float Wx[4], Wy[4], ux[4], uy[4];
    const int base = g * 4 * D_MODEL + d;
#pragma unroll
    for (int m = 0; m < 4; ++m) {
        const int idx  = base + m * D_MODEL;
        const float r  = r_[idx];
        const float th = th_[idx];
        const float Re = Rre_[idx];
        const float Im = Rim_[idx];

        // hw trig in revolutions: th/(2pi) in [0,1), no range reduction
        const float rev = th * 0.15915494309189535f;
        const float sn  = __builtin_amdgcn_sinf(rev);
        const float cs  = __builtin_amdgcn_cosf(rev);
        const float wx  = r * cs;
        const float wy  = r * sn;
        Wx[m] = wx; Wy[m] = wy;

        // A = (Re + i Im) * W^{-1} = (Re + i Im) * conj(W) / r^2
        const float invr2 = __builtin_amdgcn_rcpf(r * r);
        const float Ax = fmaf(Re, wx,   Im * wy)  * invr2;
        const float Ay = fmaf(Im, wx, -(Re * wy)) * invr2;

        // s = W^64 via 6 complex squarings
        float sx = wx, sy = wy;
#pragma unroll
        for (int q = 0; q < 6; ++q) {
            const float nx = fmaf(sx, sx, -(sy * sy));
            sy = 2.0f * sx * sy;
            sx = nx;
        }

        // P = (W^64)^c, branchless 6-bit binexp (c < 64)
        float px = 1.0f, py = 0.0f;
#pragma unroll
        for (int b = 0; b < 6; ++b) {
            const float nx = fmaf(px, sx, -(py * sy));
            const float ny = fmaf(px, sy,   py * sx);
            const bool bit = (c >> b) & 1;
            px = bit ? nx : px;
            py = bit ? ny : py;
            if (b < 5) {
                const float qx = fmaf(sx, sx, -(sy * sy));
                sy = 2.0f * sx * sy;
                sx = qx;
            }
        }

        // u = A * P = (Re + i Im) * p^(t0 - 1)
        ux[m] = fmaf(Ax, px, -(Ay * py));
        uy[m] = fmaf(Ax, py,   Ay * px);
    }

    float* rowp = out + (size_t)d * SEQ_L + t0;

    // ---- two 32-t halves; seed amortized over 64 t ----
#pragma unroll
    for (int h = 0; h < 2; ++h) {
        float vals[32];
#pragma unroll
        for (int j = 0; j < 32; ++j) vals[j] = 0.0f;

#pragma unroll
        for (int j = 0; j < 32; ++j) {
#pragma unroll
            for (int m = 0; m < 4; ++m) {
                vals[j] += ux[m];
                const float t  = uy[m] * Wy[m];
                const float nx = fmaf(ux[m], Wx[m], -t);
                uy[m] = fmaf(ux[m], Wy[m], uy[m] * Wx[m]);
                ux[m] = nx;
            }
        }

        // reduce the 4 mode groups (lanes differ only in g)
#pragma unroll
        for (int j = 0; j < 32; ++j) {
            vals[j] += __shfl_xor(vals[j], 16);
            vals[j] += __shfl_xor(vals[j], 32);
        }

        if (g == 0) {
            if (c == 0 && h == 0) vals[0] = h0_[d];
            float* p = rowp + h * 32;
#pragma unroll
            for (int q = 0; q < 8; ++q)
                *(float4*)(p + 4 * q) =
                    make_float4(vals[4*q], vals[4*q+1], vals[4*q+2], vals[4*q+3]);
        }
    }
}

extern "C" void kernel_launch(void* const* d_in, const int* in_sizes, int n_in,
                              void* d_out, int out_size, void* d_ws, size_t ws_size,
                              hipStream_t stream) {
    // inputs: [0]=L (scalar), [1]=r, [2]=theta, [3]=R_re, [4]=R_im, [5]=h_0
    const float* r_   = (const float*)d_in[1];
    const float* th_  = (const float*)d_in[2];
    const float* Rre_ = (const float*)d_in[3];
    const float* Rim_ = (const float*)d_in[4];
    const float* h0_  = (const float*)d_in[5];
    float* out = (float*)d_out;

    const int total_threads = D_MODEL * 4 * 64;    // 262144 (4096 waves)
    const int block = 256;
    const int grid  = total_threads / block;       // 1024 blocks
    pcmf_kernel<<<grid, block, 0, stream>>>(r_, th_, Rre_, Rim_, h0_, out);
}

// Round 5
// 20.616 us; speedup vs baseline: 1.5446x; 1.0043x over previous
//
#include <hip/hip_runtime.h>

#define D_MODEL 1024
#define SEQ_L   4096
#define TC      16                 // timesteps per thread
#define CPR     (SEQ_L / TC)       // 256 chunks per row = threads per block

#define INV2PI 0.15915494309189535f

// out[d][t]: t==0 -> h0[d]; t>=1 -> sum_m Re( (Rre+i*Rim) * (r e^{i th})^(t-1) )
//
// One block per d (d = blockIdx.x -> all parameter loads are scalar/uniform).
// Thread c = threadIdx.x owns t = 16c .. 16c+15 for ALL 16 modes: zero
// cross-lane traffic, zero LDS. Per mode: direct seed at q0 = 16c-1 using hw
// transcendentals in revolution domain (fract(q0*theta/2pi), exp2(q0*log2 r)),
// then 16-step complex rotation u *= W, accumulating Re(u).
// Modes in 2 passes of 8 to bound register pressure (~70 VGPR).
__global__ __launch_bounds__(256, 4) void pcmf_kernel(
    const float* __restrict__ r_,
    const float* __restrict__ th_,
    const float* __restrict__ Rre_,
    const float* __restrict__ Rim_,
    const float* __restrict__ h0_,
    float* __restrict__ out)
{
    const int d  = blockIdx.x;          // 0..1023, block-uniform
    const int c  = threadIdx.x;         // 0..255
    const int t0 = c * TC;
    const float q0f = (float)(t0 - 1);  // power index of first element

    float vals[TC];
#pragma unroll
    for (int j = 0; j < TC; ++j) vals[j] = 0.0f;

#pragma unroll
    for (int pass = 0; pass < 2; ++pass) {
        float Wx[8], Wy[8], ux[8], uy[8];

#pragma unroll
        for (int m = 0; m < 8; ++m) {
            const int idx  = (pass * 8 + m) * D_MODEL + d;   // uniform -> s_load
            const float r  = r_[idx];
            const float th = th_[idx];
            const float Re = Rre_[idx];
            const float Im = Rim_[idx];

            // one-step rotation factor W = r * e^{i th} (hw trig, revolutions)
            const float rev = th * INV2PI;
            const float sn1 = __builtin_amdgcn_sinf(rev);
            const float cs1 = __builtin_amdgcn_cosf(rev);
            Wx[m] = r * cs1;
            Wy[m] = r * sn1;

            // seed u = (Re + i Im) * r^q0 * e^{i q0 th}
            const float fr  = __builtin_amdgcn_fractf(q0f * rev);
            const float sn0 = __builtin_amdgcn_sinf(fr);
            const float cs0 = __builtin_amdgcn_cosf(fr);
            const float dec = __builtin_amdgcn_exp2f(q0f * __builtin_amdgcn_logf(r));
            const float x = dec * cs0;
            const float y = dec * sn0;
            ux[m] = fmaf(Re, x, -(Im * y));
            uy[m] = fmaf(Re, y,   Im * x);
        }

        // 16 steps x 8 independent rotation chains (5 VALU per mode-step)
#pragma unroll
        for (int j = 0; j < TC; ++j) {
#pragma unroll
            for (int m = 0; m < 8; ++m) {
                vals[j] += ux[m];
                const float t  = uy[m] * Wy[m];
                const float nx = fmaf(ux[m], Wx[m], -t);
                uy[m] = fmaf(ux[m], Wy[m], uy[m] * Wx[m]);
                ux[m] = nx;
            }
        }
    }

    if (c == 0) vals[0] = h0_[d];

    float* p = out + (size_t)d * SEQ_L + t0;
#pragma unroll
    for (int q = 0; q < TC / 4; ++q)
        *(float4*)(p + 4 * q) =
            make_float4(vals[4*q], vals[4*q+1], vals[4*q+2], vals[4*q+3]);
}

extern "C" void kernel_launch(void* const* d_in, const int* in_sizes, int n_in,
                              void* d_out, int out_size, void* d_ws, size_t ws_size,
                              hipStream_t stream) {
    // inputs: [0]=L (scalar), [1]=r, [2]=theta, [3]=R_re, [4]=R_im, [5]=h_0
    const float* r_   = (const float*)d_in[1];
    const float* th_  = (const float*)d_in[2];
    const float* Rre_ = (const float*)d_in[3];
    const float* Rim_ = (const float*)d_in[4];
    const float* h0_  = (const float*)d_in[5];
    float* out = (float*)d_out;

    pcmf_kernel<<<D_MODEL, CPR, 0, stream>>>(r_, th_, Rre_, Rim_, h0_, out);
}

// Round 6
// 17.377 us; speedup vs baseline: 1.8324x; 1.1864x over previous
//
#include <hip/hip_runtime.h>

#define D_MODEL 1024
#define SEQ_L   4096
#define TC      16                 // timesteps per thread
#define CPR     (SEQ_L / TC)       // 256 threads per block (one block per d)

#define INV2PI 0.15915494309189535f

// out[d][t]: t==0 -> h0[d]; t>=1 -> sum_m Re( (Rre+i*Rim) * (r e^{i th})^(t-1) )
//
// One block per d (params block-uniform -> scalar loads). Thread c owns
// t = 16c..16c+15 for ALL 16 modes; zero cross-lane traffic.
// Per mode: direct seed at q0 = 16c-1 via hw transcendentals in revolution
// domain, then ORDER-2 REAL recurrence v_q = a*v_{q-1} - b*v_{q-2}
// (a = 2 r cos th, b = r^2; roots p,conj(p) inside unit circle -> stable).
// 3 VALU per mode-step (vs 5 for complex rotation).
__global__ __launch_bounds__(256, 4) void pcmf_kernel(
    const float* __restrict__ r_,
    const float* __restrict__ th_,
    const float* __restrict__ Rre_,
    const float* __restrict__ Rim_,
    const float* __restrict__ h0_,
    float* __restrict__ out)
{
    const int d  = blockIdx.x;          // 0..1023, block-uniform
    const int c  = threadIdx.x;         // 0..255
    const int t0 = c * TC;
    const float q0f = (float)(t0 - 1);  // power index of first element

    float a[16], b[16], v1[16], v2[16];

#pragma unroll
    for (int m = 0; m < 16; ++m) {
        const int idx  = m * D_MODEL + d;    // uniform -> s_load
        const float r  = r_[idx];
        const float th = th_[idx];
        const float Re = Rre_[idx];
        const float Im = Rim_[idx];

        // W = r e^{i th} (hw trig in revolutions; th/(2pi) in [0,1))
        const float rev = th * INV2PI;
        const float sn1 = __builtin_amdgcn_sinf(rev);
        const float cs1 = __builtin_amdgcn_cosf(rev);
        const float Wx  = r * cs1;
        const float Wy  = r * sn1;

        a[m] = 2.0f * Wx;                // 2 r cos th
        b[m] = r * r;                    // r^2

        // u = (Re + i Im) * r^q0 * e^{i q0 th}
        const float fr  = __builtin_amdgcn_fractf(q0f * rev);
        const float sn0 = __builtin_amdgcn_sinf(fr);
        const float cs0 = __builtin_amdgcn_cosf(fr);
        const float dec = __builtin_amdgcn_exp2f(q0f * __builtin_amdgcn_logf(r));
        const float x   = dec * cs0;
        const float y   = dec * sn0;
        const float uxm = fmaf(Re, x, -(Im * y));   // v_{q0} = Re(u)
        const float uym = fmaf(Re, y,   Im * x);

        v2[m] = uxm;                                // v_{q0}
        v1[m] = fmaf(uxm, Wx, -(uym * Wy));         // v_{q0+1} = Re(u*W)
    }

    float vals[TC];
#pragma unroll
    for (int j = 0; j < TC; ++j) vals[j] = 0.0f;

#pragma unroll
    for (int m = 0; m < 16; ++m) {
        vals[0] += v2[m];
        vals[1] += v1[m];
    }

    // ---- 14 steps x 16 independent order-2 chains: 3 VALU per mode-step ----
#pragma unroll
    for (int j = 2; j < TC; ++j) {
#pragma unroll
        for (int m = 0; m < 16; ++m) {
            const float t  = b[m] * v2[m];
            const float vn = fmaf(a[m], v1[m], -t);
            vals[j] += vn;
            v2[m] = v1[m];
            v1[m] = vn;
        }
    }

    if (c == 0) vals[0] = h0_[d];

    float* p = out + (size_t)d * SEQ_L + t0;
#pragma unroll
    for (int q = 0; q < TC / 4; ++q)
        *(float4*)(p + 4 * q) =
            make_float4(vals[4*q], vals[4*q+1], vals[4*q+2], vals[4*q+3]);
}

extern "C" void kernel_launch(void* const* d_in, const int* in_sizes, int n_in,
                              void* d_out, int out_size, void* d_ws, size_t ws_size,
                              hipStream_t stream) {
    // inputs: [0]=L (scalar), [1]=r, [2]=theta, [3]=R_re, [4]=R_im, [5]=h_0
    const float* r_   = (const float*)d_in[1];
    const float* th_  = (const float*)d_in[2];
    const float* Rre_ = (const float*)d_in[3];
    const float* Rim_ = (const float*)d_in[4];
    const float* h0_  = (const float*)d_in[5];
    float* out = (float*)d_out;

    pcmf_kernel<<<D_MODEL, CPR, 0, stream>>>(r_, th_, Rre_, Rim_, h0_, out);
}